// Round 1
// baseline (236.204 us; speedup 1.0000x reference)
//
#include <hip/hip_runtime.h>
#include <hip/hip_bf16.h>

// Problem constants (match reference)
#define N_TOKENS 16384
#define IN_F 1024
#define OUT_F 1024
#define NB 256      // number of sparse blocks
#define BH 32       // block height (output dim)
#define BW 32       // block width (input dim)
#define NRB 32      // OUT_F / BH row blocks
#define T_TILE 32   // tokens per workgroup
#define LDS_STRIDE (IN_F + 8)  // bf16 elements; +8 pad -> row stride 2064 B (16B aligned, 2-way max bank alias)

typedef short short8 __attribute__((ext_vector_type(8)));   // 8 bf16 = 4 VGPRs (MFMA A/B frag)
typedef short short4v __attribute__((ext_vector_type(4)));
typedef float float4v __attribute__((ext_vector_type(4)));  // MFMA C/D frag

// fp32 -> bf16 round-to-nearest-even (inputs are finite normals; no NaN path needed)
__device__ __forceinline__ short f2bf(float f) {
    unsigned u = __builtin_bit_cast(unsigned, f);
    u += 0x7fffu + ((u >> 16) & 1u);
    return (short)(u >> 16);
}

__global__ __launch_bounds__(256, 2) void spmm_mfma_kernel(
    const float* __restrict__ x,
    const float* __restrict__ wd,
    const float* __restrict__ bias,
    const int* __restrict__ brow,
    const int* __restrict__ bcol,
    float* __restrict__ out)
{
    // LDS: 66048 + 8192 + 512 + 128 = 74880 B -> 2 workgroups/CU
    __shared__ short xs[T_TILE * LDS_STRIDE];      // x tile, bf16
    __shared__ unsigned char lists[NRB][NB];       // per-row block id lists (CSR-ish)
    __shared__ short colOf[NB];                    // block_col per block
    __shared__ int counts[NRB];

    const int tid = threadIdx.x;
    const int n0 = blockIdx.x * T_TILE;

    if (tid < NRB) counts[tid] = 0;
    __syncthreads();

    // Build row-grouped lists: one thread per sparse block. Order within a row
    // is nondeterministic (LDS atomics) -> fp sum order varies; threshold covers it.
    {
        const int b = tid;                // 256 threads == 256 blocks
        const int r = brow[b];
        colOf[b] = (short)bcol[b];
        const int slot = atomicAdd(&counts[r], 1);
        lists[r][slot] = (unsigned char)b;
    }

    // Stage x tile -> LDS as bf16. One row (1024 floats) per iteration,
    // thread t covers cols 4t..4t+3: perfectly coalesced dwordx4 loads.
    {
        const float* xp = x + (size_t)n0 * IN_F + 4 * tid;
        short* sp = xs + 4 * tid;
#pragma unroll 4
        for (int it = 0; it < T_TILE; ++it) {
            const float4 v = *(const float4*)(xp + it * IN_F);
            short4v s;
            s[0] = f2bf(v.x); s[1] = f2bf(v.y); s[2] = f2bf(v.z); s[3] = f2bf(v.w);
            *(short4v*)(sp + it * LDS_STRIDE) = s;
        }
    }
    __syncthreads();

    const int lane = tid & 63;
    const int wave = tid >> 6;
    const int quad = lane >> 4;
    const int l16  = lane & 15;
    const int tw = wave & 1;   // token half: tokens tw*16 .. tw*16+15
    const int oh = wave >> 1;  // output half: outputs oh*16 .. oh*16+15

    // A frag: A[m=l16][k=quad*8+j] = x[tok tw*16+l16][c*32 + quad*8 + j]
    const short* aptr = xs + (tw * 16 + l16) * LDS_STRIDE + quad * 8;
    // B frag: B[k=quad*8+j][n=l16] = W[b][oh*16+l16][quad*8+j]
    const float* wbase = wd + (oh * 16 + l16) * BW + quad * 8;

    for (int r = 0; r < NRB; ++r) {
        float4v acc = {0.f, 0.f, 0.f, 0.f};
        const int cnt = counts[r];
        int b = (cnt > 0) ? (int)lists[r][0] : 0;
        int c = colOf[b];
        for (int k = 0; k < cnt; ++k) {
            const int bn = (k + 1 < cnt) ? (int)lists[r][k + 1] : 0;  // prefetch indices
            const short8 afrag = *(const short8*)(aptr + c * BW);     // ds_read_b128
            const float* wp = wbase + b * (BH * BW);
            const float4 w0 = *(const float4*)(wp);
            const float4 w1 = *(const float4*)(wp + 4);
            const int cn = colOf[bn];
            short8 bfrag;
            bfrag[0] = f2bf(w0.x); bfrag[1] = f2bf(w0.y);
            bfrag[2] = f2bf(w0.z); bfrag[3] = f2bf(w0.w);
            bfrag[4] = f2bf(w1.x); bfrag[5] = f2bf(w1.y);
            bfrag[6] = f2bf(w1.z); bfrag[7] = f2bf(w1.w);
            acc = __builtin_amdgcn_mfma_f32_16x16x32_bf16(afrag, bfrag, acc, 0, 0, 0);
            b = bn; c = cn;
        }
        // C/D: token_local = tw*16 + quad*4 + reg ; o = r*32 + oh*16 + l16
        const int ob = r * BH + oh * 16 + l16;
        const float bv = bias[ob];
        float* op = out + (size_t)(n0 + tw * 16 + quad * 4) * OUT_F + ob;
#pragma unroll
        for (int reg = 0; reg < 4; ++reg) {
            op[reg * OUT_F] = acc[reg] + bv;   // rows with zero blocks still get bias
        }
    }
}

extern "C" void kernel_launch(void* const* d_in, const int* in_sizes, int n_in,
                              void* d_out, int out_size, void* d_ws, size_t ws_size,
                              hipStream_t stream) {
    const float* x    = (const float*)d_in[0];
    const float* wd   = (const float*)d_in[1];
    const float* bias = (const float*)d_in[2];
    const int* brow   = (const int*)d_in[3];
    const int* bcol   = (const int*)d_in[4];
    float* out = (float*)d_out;

    dim3 grid(N_TOKENS / T_TILE);  // 512 workgroups, 2/CU
    spmm_mfma_kernel<<<grid, 256, 0, stream>>>(x, wd, bias, brow, bcol, out);
}

// Round 2
// 164.277 us; speedup vs baseline: 1.4378x; 1.4378x over previous
//
#include <hip/hip_runtime.h>

// Problem constants (match reference)
#define N_TOKENS 16384
#define IN_F 1024
#define OUT_F 1024
#define NB 256      // sparse blocks
#define BH 32
#define BW 32
#define NRB 32      // OUT_F / BH
#define T_TILE 16   // tokens per workgroup
#define XS_STRIDE 1032           // shorts per LDS row (1024 + 8 pad; 2064 B, 16B-aligned)
#define MAX_SCHED (NB + NRB)     // 288 max schedule entries (empty rows get flush-only slots)
#define WF_SLOT_SHORTS 1024      // per entry: 2 oh-frags x 64 lanes x 8 bf16 = 2048 B

// Workspace layout (bytes). Total ~592 KB.
#define WS_WF_BYTES   (MAX_SCHED * WF_SLOT_SHORTS * 2)   // 589824
#define WS_SCHED_OFF  WS_WF_BYTES                         // int[MAX_SCHED]
#define WS_POS_OFF    (WS_SCHED_OFF + MAX_SCHED * 4)      // int[NB] pos_of
#define WS_WSTART_OFF (WS_POS_OFF + NB * 4)               // int[5]

typedef short short8 __attribute__((ext_vector_type(8)));   // MFMA A/B frag (8 bf16)
typedef float float4v __attribute__((ext_vector_type(4)));  // MFMA C/D frag

// fp32 -> bf16 round-to-nearest-even (inputs finite)
__device__ __forceinline__ short f2bf(float f) {
    unsigned u = __builtin_bit_cast(unsigned, f);
    u += 0x7fffu + ((u >> 16) & 1u);
    return (short)(u >> 16);
}

// ---------------------------------------------------------------------------
// Prep 1: build flattened schedule, sorted by (wave = r%4, r, b).
// Entry pack: bits[4:0]=c, bits[9:5]=r, bit[10]=flush(last entry of row r).
// Empty rows emit a flush-only entry with a zeroed W-fragment slot.
// Also writes pos_of[b] (schedule position of block b) and wstart[0..4].
// ---------------------------------------------------------------------------
__global__ void prep_sched_kernel(const int* __restrict__ brow, const int* __restrict__ bcol,
                                  int* __restrict__ sched, int* __restrict__ pos_of,
                                  int* __restrict__ wstart, short* __restrict__ wf)
{
    __shared__ int sr[NB], sc[NB], scnt[NRB];
    const int tid = threadIdx.x;  // 64 threads
    for (int i = tid; i < NB; i += 64) { sr[i] = brow[i]; sc[i] = bcol[i]; }
    __syncthreads();
    if (tid < NRB) {
        int c = 0;
        for (int b = 0; b < NB; ++b) c += (sr[b] == tid);
        scnt[tid] = c;
    }
    __syncthreads();
    if (tid < NRB) {
        const int r = tid, w = r & 3, i = r >> 2;
        int start = 0;
        for (int rr = 0; rr < NRB; ++rr) {
            const int ww = rr & 3, ii = rr >> 2;
            const int adj = scnt[rr] > 0 ? scnt[rr] : 1;
            if (ww < w || (ww == w && ii < i)) start += adj;
        }
        int pos = start;
        const int cnt = scnt[r];
        if (cnt == 0) {
            sched[pos] = (r << 5) | (1 << 10);
            int4 z = {0, 0, 0, 0};
            int4* dst = (int4*)(wf + (size_t)pos * WF_SLOT_SHORTS);
            for (int q = 0; q < WF_SLOT_SHORTS / 8; ++q) dst[q] = z;
        } else {
            int emitted = 0;
            for (int b = 0; b < NB; ++b) {
                if (sr[b] == r) {
                    ++emitted;
                    const int fl = (emitted == cnt) ? (1 << 10) : 0;
                    sched[pos] = sc[b] | (r << 5) | fl;
                    pos_of[b] = pos;
                    ++pos;
                }
            }
        }
    }
    if (tid < 5) {  // wstart[w] = sum of adjusted counts of rows with r%4 < w
        int acc = 0;
        for (int rr = 0; rr < NRB; ++rr) {
            const int adj = scnt[rr] > 0 ? scnt[rr] : 1;
            if ((rr & 3) < tid) acc += adj;
        }
        wstart[tid] = acc;
    }
}

// ---------------------------------------------------------------------------
// Prep 2: W fp32 -> bf16 B-fragments, written in SCHEDULE order.
// Frag element: B[k=quad*8+j][n=oh*16+l16] = W[b][oh*16+l16][quad*8+j]
// stored at wf[((pos*2+oh)*64 + lane)*8 + j].
// One thread per (b, oh, lane): reads 32 B contiguous, writes 16 B contiguous.
// ---------------------------------------------------------------------------
__global__ void prep_w_kernel(const float* __restrict__ wd, const int* __restrict__ pos_of,
                              short* __restrict__ wf)
{
    const int g = blockIdx.x * blockDim.x + threadIdx.x;  // 32768 threads
    const int lane = g & 63;
    const int oh = (g >> 6) & 1;
    const int b = g >> 7;
    const int l16 = lane & 15, quad = lane >> 4;
    const int pos = pos_of[b];
    const float* src = wd + (size_t)b * (BH * BW) + (oh * 16 + l16) * BW + quad * 8;
    const float4 w0 = *(const float4*)src;
    const float4 w1 = *(const float4*)(src + 4);
    short8 o;
    o[0] = f2bf(w0.x); o[1] = f2bf(w0.y); o[2] = f2bf(w0.z); o[3] = f2bf(w0.w);
    o[4] = f2bf(w1.x); o[5] = f2bf(w1.y); o[6] = f2bf(w1.z); o[7] = f2bf(w1.w);
    *(short8*)(wf + (((size_t)pos * 2 + oh) * 64 + lane) * 8) = o;
}

// ---------------------------------------------------------------------------
// Main: 1024 WGs x 256 thr (4 waves). WG owns 16 tokens (x tile in LDS, bf16).
// Wave w processes rows r%4==w via its contiguous schedule range, 2-deep
// software pipeline: entry/A-frag/W-frags prefetched. W address = f(loop idx).
// ---------------------------------------------------------------------------
__global__ __launch_bounds__(256, 4) void spmm_main_kernel(
    const float* __restrict__ x, const float* __restrict__ bias,
    const short* __restrict__ wf, const int* __restrict__ sched_g,
    const int* __restrict__ wstart_g, float* __restrict__ out)
{
    __shared__ short xs[T_TILE * XS_STRIDE];   // 33024 B
    __shared__ int ssched[MAX_SCHED];          // 1152 B
    __shared__ int swstart[5];

    const int tid = threadIdx.x;
    const int n0 = blockIdx.x * T_TILE;

    // Stage x tile -> LDS bf16. 2 rows/iter, 128 threads/row, 8 cols each:
    // wave reads 2 KB contiguous fp32, writes 16 B-aligned short8.
    {
        const int tr = tid >> 7;       // 0/1
        const int tc = tid & 127;      // col octet
        const float* xp = x + (size_t)(n0 + tr) * IN_F + tc * 8;
        short* sp = xs + tr * XS_STRIDE + tc * 8;
#pragma unroll
        for (int it = 0; it < T_TILE / 2; ++it) {
            const float4 a = *(const float4*)xp;
            const float4 b = *(const float4*)(xp + 4);
            short8 s;
            s[0] = f2bf(a.x); s[1] = f2bf(a.y); s[2] = f2bf(a.z); s[3] = f2bf(a.w);
            s[4] = f2bf(b.x); s[5] = f2bf(b.y); s[6] = f2bf(b.z); s[7] = f2bf(b.w);
            *(short8*)sp = s;
            xp += 2 * IN_F;
            sp += 2 * XS_STRIDE;
        }
    }
    ssched[tid] = sched_g[tid];
    if (tid < MAX_SCHED - 256) ssched[256 + tid] = sched_g[256 + tid];
    if (tid < 5) swstart[tid] = wstart_g[tid];
    __syncthreads();

    const int lane = tid & 63;
    const int wave = tid >> 6;
    const int l16 = lane & 15, quad = lane >> 4;

    const int s = swstart[wave];
    const int e = swstart[wave + 1];   // e - s >= 8 always (8 rows per wave)

    const short* xrow = xs + l16 * XS_STRIDE + quad * 8;  // + c*32
    const short* wfl = wf + lane * 8;                     // + (pos*2+oh)*512

    // ---- pipeline prologue (2-deep) ----
    int e0 = ssched[s];
    int e1 = ssched[(s + 1 < MAX_SCHED) ? s + 1 : MAX_SCHED - 1];
    short8 a0 = *(const short8*)(xrow + (e0 & 31) * BW);
    short8 wA0 = *(const short8*)(wfl + (size_t)(s * 2 + 0) * 512);
    short8 wB0 = *(const short8*)(wfl + (size_t)(s * 2 + 1) * 512);
    const int p1 = (s + 1 < e) ? s + 1 : e - 1;
    short8 wA1 = *(const short8*)(wfl + (size_t)(p1 * 2 + 0) * 512);
    short8 wB1 = *(const short8*)(wfl + (size_t)(p1 * 2 + 1) * 512);

    float4v acc0 = {0.f, 0.f, 0.f, 0.f};
    float4v acc1 = {0.f, 0.f, 0.f, 0.f};

    for (int k = s; k < e; ++k) {
        // prefetch stage k+2
        const int kp = (k + 2 < e) ? k + 2 : e - 1;
        const int ei = (k + 2 < MAX_SCHED) ? k + 2 : MAX_SCHED - 1;
        const int ep = ssched[ei];
        short8 wA2 = *(const short8*)(wfl + (size_t)(kp * 2 + 0) * 512);
        short8 wB2 = *(const short8*)(wfl + (size_t)(kp * 2 + 1) * 512);
        short8 a1 = *(const short8*)(xrow + (e1 & 31) * BW);

        acc0 = __builtin_amdgcn_mfma_f32_16x16x32_bf16(a0, wA0, acc0, 0, 0, 0);
        acc1 = __builtin_amdgcn_mfma_f32_16x16x32_bf16(a0, wB0, acc1, 0, 0, 0);

        if (e0 & (1 << 10)) {  // wave-uniform flush: last entry of row r
            const int r = (e0 >> 5) & 31;
            const int ob = r * BH + l16;
            const float bv0 = bias[ob];
            const float bv1 = bias[ob + 16];
            float* op = out + (size_t)(n0 + quad * 4) * OUT_F + ob;
#pragma unroll
            for (int g = 0; g < 4; ++g) {   // token = quad*4 + g (C/D layout)
                op[g * OUT_F] = acc0[g] + bv0;
                op[g * OUT_F + 16] = acc1[g] + bv1;
            }
            acc0 = (float4v){0.f, 0.f, 0.f, 0.f};
            acc1 = (float4v){0.f, 0.f, 0.f, 0.f};
        }
        e0 = e1; e1 = ep;
        a0 = a1;
        wA0 = wA1; wB0 = wB1;
        wA1 = wA2; wB1 = wB2;
    }
}

extern "C" void kernel_launch(void* const* d_in, const int* in_sizes, int n_in,
                              void* d_out, int out_size, void* d_ws, size_t ws_size,
                              hipStream_t stream) {
    const float* x    = (const float*)d_in[0];
    const float* wd   = (const float*)d_in[1];
    const float* bias = (const float*)d_in[2];
    const int* brow   = (const int*)d_in[3];
    const int* bcol   = (const int*)d_in[4];
    float* out = (float*)d_out;

    char* ws = (char*)d_ws;                 // needs ~592 KB
    short* wf     = (short*)ws;
    int* sched    = (int*)(ws + WS_SCHED_OFF);
    int* pos_of   = (int*)(ws + WS_POS_OFF);
    int* wstart   = (int*)(ws + WS_WSTART_OFF);

    prep_sched_kernel<<<1, 64, 0, stream>>>(brow, bcol, sched, pos_of, wstart, wf);
    prep_w_kernel<<<NB * 128 / 256, 256, 0, stream>>>(wd, pos_of, wf);
    spmm_main_kernel<<<N_TOKENS / T_TILE, 256, 0, stream>>>(x, bias, wf, sched, wstart, out);
}

// Round 3
// 137.365 us; speedup vs baseline: 1.7195x; 1.1959x over previous
//
#include <hip/hip_runtime.h>

// Problem constants (match reference)
#define N_TOKENS 16384
#define IN_F 1024
#define OUT_F 1024
#define NB 256      // sparse blocks
#define BH 32
#define BW 32
#define NRB 32      // OUT_F / BH
#define T_TILE 32   // tokens per workgroup
#define XS_STRIDE 1040           // shorts/row = 2080 B; dword stride 520 == 8 (mod 32) -> balanced banks
#define MAX_SCHED (NB + NRB)     // 288 max real schedule entries
#define SCHED_PAD (MAX_SCHED + 2)// 290: +2 slots so the 2-deep pipeline can overread safely
#define WF_SLOT_SHORTS 1024      // per entry: 2 oh-frags x 64 lanes x 8 bf16 = 2048 B

// Workspace layout (bytes). Total ~596 KB.
#define WS_WF_BYTES   (SCHED_PAD * WF_SLOT_SHORTS * 2)    // 593920
#define WS_SCHED_OFF  WS_WF_BYTES                          // int[SCHED_PAD]
#define WS_POS_OFF    (WS_SCHED_OFF + SCHED_PAD * 4)       // int[NB]
#define WS_WSTART_OFF (WS_POS_OFF + NB * 4)                // int[5]

typedef short short8 __attribute__((ext_vector_type(8)));   // MFMA A/B frag (8 bf16)
typedef float float4v __attribute__((ext_vector_type(4)));  // MFMA C/D frag

// fp32 -> bf16 round-to-nearest-even (inputs finite)
__device__ __forceinline__ short f2bf(float f) {
    unsigned u = __builtin_bit_cast(unsigned, f);
    u += 0x7fffu + ((u >> 16) & 1u);
    return (short)(u >> 16);
}

// ---------------------------------------------------------------------------
// Prep 1 (256 thr, ~3 us): schedule sorted by (wave = r%4, r), entries of a
// row contiguous (order within row nondeterministic via LDS atomics -- fp sum
// order only). Entry pack: bits[4:0]=c, bits[9:5]=r, bit[10]=flush.
// Empty rows (prob ~e^-8 per row, essentially never) get a flush-only entry
// with a zeroed wf slot. pos_of[b] = schedule position of block b.
// wstart[w] = first position of wave w's range, wstart[4] = total.
// ---------------------------------------------------------------------------
__global__ void prep_sched_kernel(const int* __restrict__ brow, const int* __restrict__ bcol,
                                  int* __restrict__ sched, int* __restrict__ pos_of,
                                  int* __restrict__ wstart, short* __restrict__ wf)
{
    __shared__ int cnt[NRB], start[NRB], cur[NRB];
    const int tid = threadIdx.x;   // 256 threads, one per sparse block
    if (tid < NRB) { cnt[tid] = 0; cur[tid] = 0; }
    __syncthreads();
    const int r = brow[tid];
    const int c = bcol[tid];
    atomicAdd(&cnt[r], 1);
    __syncthreads();
    if (tid < NRB) {               // start[r]: exclusive scan in (r&3 major, r>>2 minor) order
        const int w = tid & 3, i = tid >> 2;
        int s = 0;
        for (int rr = 0; rr < NRB; ++rr) {
            const int adj = cnt[rr] > 0 ? cnt[rr] : 1;
            const int ww = rr & 3, ii = rr >> 2;
            if (ww < w || (ww == w && ii < i)) s += adj;
        }
        start[tid] = s;
    }
    if (tid >= 64 && tid < 69) {   // wstart[0..4]
        const int w = tid - 64;
        int s = 0;
        for (int rr = 0; rr < NRB; ++rr) {
            const int adj = cnt[rr] > 0 ? cnt[rr] : 1;
            if ((rr & 3) < w) s += adj;
        }
        wstart[w] = s;
    }
    __syncthreads();
    const int slot = atomicAdd(&cur[r], 1);
    const int pos = start[r] + slot;
    sched[pos] = c | (r << 5) | ((slot == cnt[r] - 1) ? (1 << 10) : 0);
    pos_of[tid] = pos;
    if (tid < NRB && cnt[tid] == 0) {   // empty-row fallback (rare)
        sched[start[tid]] = (tid << 5) | (1 << 10);
        int4 z = {0, 0, 0, 0};
        int4* dst = (int4*)(wf + (size_t)start[tid] * WF_SLOT_SHORTS);
        for (int q = 0; q < WF_SLOT_SHORTS / 8; ++q) dst[q] = z;
    }
}

// ---------------------------------------------------------------------------
// Prep 2: W fp32 -> bf16 B-fragments in SCHEDULE order.
// B[k=quad*8+j][n=oh*16+l16] = W[b][oh*16+l16][quad*8+j]
// stored at wf[pos*1024 + oh*512 + lane*8 + j].
// ---------------------------------------------------------------------------
__global__ void prep_w_kernel(const float* __restrict__ wd, const int* __restrict__ pos_of,
                              short* __restrict__ wf)
{
    const int g = blockIdx.x * blockDim.x + threadIdx.x;  // 32768 threads
    const int lane = g & 63;
    const int oh = (g >> 6) & 1;
    const int b = g >> 7;
    const int l16 = lane & 15, quad = lane >> 4;
    const int pos = pos_of[b];
    const float* src = wd + (size_t)b * (BH * BW) + (oh * 16 + l16) * BW + quad * 8;
    const float4 w0 = *(const float4*)src;
    const float4 w1 = *(const float4*)(src + 4);
    short8 o;
    o[0] = f2bf(w0.x); o[1] = f2bf(w0.y); o[2] = f2bf(w0.z); o[3] = f2bf(w0.w);
    o[4] = f2bf(w1.x); o[5] = f2bf(w1.y); o[6] = f2bf(w1.z); o[7] = f2bf(w1.w);
    *(short8*)(wf + (size_t)pos * WF_SLOT_SHORTS + oh * 512 + lane * 8) = o;
}

// ---------------------------------------------------------------------------
// Main: 512 WGs x 256 thr (4 waves), 2 WGs/CU (LDS-bound), one resident pass.
// WG owns 32 tokens. Wave w processes rows r%4==w over its contiguous
// schedule range; 2 token-groups -> 4 MFMAs per entry. 2-deep software
// pipeline; wf address is a pure function of the loop index (no clamps --
// the +2 pad slots absorb the overread; overread values are never consumed).
// ---------------------------------------------------------------------------
__global__ __launch_bounds__(256, 2) void spmm_main_kernel(
    const float* __restrict__ x, const float* __restrict__ bias,
    const short* __restrict__ wf, const int* __restrict__ sched_g,
    const int* __restrict__ wstart_g, float* __restrict__ out)
{
    __shared__ short xs[T_TILE * XS_STRIDE];   // 66560 B
    __shared__ int ssched[SCHED_PAD];          // 1160 B
    __shared__ int swstart[5];

    const int tid = threadIdx.x;
    const int n0 = blockIdx.x * T_TILE;

    // Stage x tile -> LDS bf16. 2 rows/iter (128 thr/row, 8 cols each):
    // coalesced 2 KB fp32 per wave-row, short8 LDS stores, balanced banks.
    {
        const int tr = tid >> 7;       // 0/1
        const int tc = tid & 127;      // col octet
        const float* xp = x + (size_t)(n0 + tr) * IN_F + tc * 8;
        short* sp = xs + tr * XS_STRIDE + tc * 8;
#pragma unroll
        for (int it = 0; it < T_TILE / 2; ++it) {
            const float4 a = *(const float4*)xp;
            const float4 b = *(const float4*)(xp + 4);
            short8 s;
            s[0] = f2bf(a.x); s[1] = f2bf(a.y); s[2] = f2bf(a.z); s[3] = f2bf(a.w);
            s[4] = f2bf(b.x); s[5] = f2bf(b.y); s[6] = f2bf(b.z); s[7] = f2bf(b.w);
            *(short8*)sp = s;
            xp += 2 * IN_F;
            sp += 2 * XS_STRIDE;
        }
    }
    ssched[tid] = sched_g[tid];
    if (tid < SCHED_PAD - 256) ssched[256 + tid] = sched_g[256 + tid];
    if (tid < 5) swstart[tid] = wstart_g[tid];
    __syncthreads();

    const int lane = tid & 63;
    const int wave = tid >> 6;
    const int l16 = lane & 15, quad = lane >> 4;

    const int s = swstart[wave];
    const int e = swstart[wave + 1];   // e - s >= 8 (8 rows per wave)

    const short* x0 = xs + l16 * XS_STRIDE + quad * 8;          // token group 0
    const short* x1 = xs + (16 + l16) * XS_STRIDE + quad * 8;   // token group 1
    const short* wfl = wf + lane * 8;                            // + k*1024 (+512 for oh=1)

    // ---- pipeline prologue (2-deep) ----
    int e0 = ssched[s];
    int e1 = ssched[s + 1];
    short8 a0_0 = *(const short8*)(x0 + (e0 & 31) * BW);
    short8 a0_1 = *(const short8*)(x1 + (e0 & 31) * BW);
    short8 wA0 = *(const short8*)(wfl + (size_t)s * WF_SLOT_SHORTS);
    short8 wB0 = *(const short8*)(wfl + (size_t)s * WF_SLOT_SHORTS + 512);
    short8 wA1 = *(const short8*)(wfl + (size_t)(s + 1) * WF_SLOT_SHORTS);
    short8 wB1 = *(const short8*)(wfl + (size_t)(s + 1) * WF_SLOT_SHORTS + 512);

    // Rolling bias (loaded one row ahead so flush stores never wait on it).
    int rn = wave;
    float bv0 = bias[rn * BH + l16];
    float bv1 = bias[rn * BH + 16 + l16];

    float4v acc00 = {0.f, 0.f, 0.f, 0.f};
    float4v acc01 = {0.f, 0.f, 0.f, 0.f};
    float4v acc10 = {0.f, 0.f, 0.f, 0.f};
    float4v acc11 = {0.f, 0.f, 0.f, 0.f};

    for (int k = s; k < e; ++k) {
        // prefetch stage k+2 (pad slots make this unconditionally safe)
        const int ep = ssched[k + 2];
        const short8 wA2 = *(const short8*)(wfl + (size_t)(k + 2) * WF_SLOT_SHORTS);
        const short8 wB2 = *(const short8*)(wfl + (size_t)(k + 2) * WF_SLOT_SHORTS + 512);
        const short8 a1_0 = *(const short8*)(x0 + (e1 & 31) * BW);
        const short8 a1_1 = *(const short8*)(x1 + (e1 & 31) * BW);

        acc00 = __builtin_amdgcn_mfma_f32_16x16x32_bf16(a0_0, wA0, acc00, 0, 0, 0);
        acc01 = __builtin_amdgcn_mfma_f32_16x16x32_bf16(a0_0, wB0, acc01, 0, 0, 0);
        acc10 = __builtin_amdgcn_mfma_f32_16x16x32_bf16(a0_1, wA0, acc10, 0, 0, 0);
        acc11 = __builtin_amdgcn_mfma_f32_16x16x32_bf16(a0_1, wB0, acc11, 0, 0, 0);

        if (e0 & (1 << 10)) {  // wave-uniform flush: last entry of row r
            const int r = (e0 >> 5) & 31;
            const int ob = r * BH + l16;
            float* op0 = out + (size_t)(n0 + quad * 4) * OUT_F + ob;
            float* op1 = out + (size_t)(n0 + 16 + quad * 4) * OUT_F + ob;
#pragma unroll
            for (int g = 0; g < 4; ++g) {   // token = tg*16 + quad*4 + g (C/D layout)
                op0[g * OUT_F]      = acc00[g] + bv0;
                op0[g * OUT_F + 16] = acc01[g] + bv1;
                op1[g * OUT_F]      = acc10[g] + bv0;
                op1[g * OUT_F + 16] = acc11[g] + bv1;
            }
            acc00 = (float4v){0.f, 0.f, 0.f, 0.f};
            acc01 = (float4v){0.f, 0.f, 0.f, 0.f};
            acc10 = (float4v){0.f, 0.f, 0.f, 0.f};
            acc11 = (float4v){0.f, 0.f, 0.f, 0.f};
            rn = (rn + 4) & 31;   // next row this wave flushes (wraps harmlessly at end)
            bv0 = bias[rn * BH + l16];
            bv1 = bias[rn * BH + 16 + l16];
        }
        e0 = e1; e1 = ep;
        a0_0 = a1_0; a0_1 = a1_1;
        wA0 = wA1; wB0 = wB1;
        wA1 = wA2; wB1 = wB2;
    }
}

extern "C" void kernel_launch(void* const* d_in, const int* in_sizes, int n_in,
                              void* d_out, int out_size, void* d_ws, size_t ws_size,
                              hipStream_t stream) {
    const float* x    = (const float*)d_in[0];
    const float* wd   = (const float*)d_in[1];
    const float* bias = (const float*)d_in[2];
    const int* brow   = (const int*)d_in[3];
    const int* bcol   = (const int*)d_in[4];
    float* out = (float*)d_out;

    char* ws = (char*)d_ws;                 // needs ~596 KB
    short* wf   = (short*)ws;
    int* sched  = (int*)(ws + WS_SCHED_OFF);
    int* pos_of = (int*)(ws + WS_POS_OFF);
    int* wstart = (int*)(ws + WS_WSTART_OFF);

    prep_sched_kernel<<<1, 256, 0, stream>>>(brow, bcol, sched, pos_of, wstart, wf);
    prep_w_kernel<<<NB * 128 / 256, 256, 0, stream>>>(wd, pos_of, wf);
    spmm_main_kernel<<<N_TOKENS / T_TILE, 256, 0, stream>>>(x, bias, wf, sched, wstart, out);
}

// Round 4
// 133.557 us; speedup vs baseline: 1.7686x; 1.0285x over previous
//
#include <hip/hip_runtime.h>

// Problem constants (match reference)
#define N_TOKENS 16384
#define IN_F 1024
#define OUT_F 1024
#define NB 256      // sparse blocks
#define BH 32
#define BW 32
#define NRB 32      // OUT_F / BH
#define T_TILE 32   // tokens per workgroup
#define NW 8        // waves per workgroup (512 threads)
#define XS_STRIDE 1040           // shorts/row; dword stride 520 == 8 (mod 32) -> 0 bank conflicts (R3 measured)
#define SCHED_ALLOC 304          // 288 max real + <=8 wave-pads + >=4 overread slots
#define WF_SLOT_SHORTS 1024      // per entry: 2 col-half frags x 64 lanes x 8 bf16 = 2048 B
#define FLUSH_BIT (1 << 10)

// Workspace layout (bytes). Total ~625 KB.
#define WS_WF_BYTES   (SCHED_ALLOC * WF_SLOT_SHORTS * 2)   // 622592
#define WS_SCHED_OFF  WS_WF_BYTES                           // int[SCHED_ALLOC]
#define WS_POS_OFF    (WS_SCHED_OFF + SCHED_ALLOC * 4)      // int[NB]
#define WS_WSTART_OFF (WS_POS_OFF + NB * 4)                 // int[NW+1]

typedef short short8 __attribute__((ext_vector_type(8)));   // MFMA A/B frag (8 bf16)
typedef float float4v __attribute__((ext_vector_type(4)));  // MFMA C/D frag

// fp32 -> bf16 round-to-nearest-even (inputs finite)
__device__ __forceinline__ short f2bf(float f) {
    unsigned u = __builtin_bit_cast(unsigned, f);
    u += 0x7fffu + ((u >> 16) & 1u);
    return (short)(u >> 16);
}

// ---------------------------------------------------------------------------
// Prep 1 (256 thr): schedule sorted by (wave = r%8 major, r/8 minor), each
// row's entries contiguous (intra-row order nondeterministic -> fp sum order
// only). Entry pack: bits[4:0]=c, bits[9:5]=r, bit[10]=flush.
// Each wave's segment is padded to EVEN length with no-flush pad entries
// (consumed after the wave's final flush -> never stored). Empty rows get a
// flush-only entry with a zeroed wf slot. Tail overread slots zeroed.
// ---------------------------------------------------------------------------
__global__ void prep_sched_kernel(const int* __restrict__ brow, const int* __restrict__ bcol,
                                  int* __restrict__ sched, int* __restrict__ pos_of,
                                  int* __restrict__ wstart, short* __restrict__ wf)
{
    __shared__ int cnt[NRB], start[NRB], cur[NRB];
    const int tid = threadIdx.x;   // 256 threads, one per sparse block
    if (tid < NRB) { cnt[tid] = 0; cur[tid] = 0; }
    __syncthreads();
    const int r = brow[tid];
    const int c = bcol[tid];
    atomicAdd(&cnt[r], 1);
    __syncthreads();
    if (tid < NRB) {               // start[r] = padded starts of earlier waves + in-wave prefix
        const int w = tid & 7;
        int s = 0;
        for (int w2 = 0; w2 < w; ++w2) {
            int t = 0;
            for (int rr = w2; rr < NRB; rr += NW) t += (cnt[rr] ? cnt[rr] : 1);
            s += (t + 1) & ~1;
        }
        for (int rr = w; rr < tid; rr += NW) s += (cnt[rr] ? cnt[rr] : 1);
        start[tid] = s;
    }
    if (tid >= 64 && tid < 64 + NW + 1) {   // wstart[0..8] (padded, even)
        const int w = tid - 64;
        int s = 0;
        for (int w2 = 0; w2 < w; ++w2) {
            int t = 0;
            for (int rr = w2; rr < NRB; rr += NW) t += (cnt[rr] ? cnt[rr] : 1);
            s += (t + 1) & ~1;
        }
        wstart[w] = s;
    }
    if (tid >= 96 && tid < 96 + NW) {       // odd-length wave -> 1 pad entry
        const int w = tid - 96;
        int base = 0;
        for (int w2 = 0; w2 < w; ++w2) {
            int t = 0;
            for (int rr = w2; rr < NRB; rr += NW) t += (cnt[rr] ? cnt[rr] : 1);
            base += (t + 1) & ~1;
        }
        int t = 0;
        for (int rr = w; rr < NRB; rr += NW) t += (cnt[rr] ? cnt[rr] : 1);
        if (t & 1) sched[base + t] = 0;     // no flush; W garbage never stored
    }
    if (tid >= 128 && tid < 136) {          // tail overread slots
        int tot = 0;
        for (int w2 = 0; w2 < NW; ++w2) {
            int t = 0;
            for (int rr = w2; rr < NRB; rr += NW) t += (cnt[rr] ? cnt[rr] : 1);
            tot += (t + 1) & ~1;
        }
        sched[tot + (tid - 128)] = 0;
    }
    __syncthreads();
    const int slot = atomicAdd(&cur[r], 1);
    const int pos = start[r] + slot;
    sched[pos] = c | (r << 5) | ((slot == cnt[r] - 1) ? FLUSH_BIT : 0);
    pos_of[tid] = pos;
    if (tid < NRB && cnt[tid] == 0) {       // empty-row fallback (bias still written)
        sched[start[tid]] = (tid << 5) | FLUSH_BIT;
        int4 z = {0, 0, 0, 0};
        int4* dst = (int4*)(wf + (size_t)start[tid] * WF_SLOT_SHORTS);
        for (int q = 0; q < WF_SLOT_SHORTS / 8; ++q) dst[q] = z;
    }
}

// ---------------------------------------------------------------------------
// Prep 2: W fp32 -> bf16 B-fragments in SCHEDULE order.
// B[k=quad*8+j][n=oh*16+l16] = W[b][oh*16+l16][quad*8+j]
// at wf[pos*1024 + oh*512 + lane*8 + j].
// ---------------------------------------------------------------------------
__global__ void prep_w_kernel(const float* __restrict__ wd, const int* __restrict__ pos_of,
                              short* __restrict__ wf)
{
    const int g = blockIdx.x * blockDim.x + threadIdx.x;  // 32768 threads
    const int lane = g & 63;
    const int oh = (g >> 6) & 1;
    const int b = g >> 7;
    const int l16 = lane & 15, quad = lane >> 4;
    const int pos = pos_of[b];
    const float* src = wd + (size_t)b * (BH * BW) + (oh * 16 + l16) * BW + quad * 8;
    const float4 w0 = *(const float4*)src;
    const float4 w1 = *(const float4*)(src + 4);
    short8 o;
    o[0] = f2bf(w0.x); o[1] = f2bf(w0.y); o[2] = f2bf(w0.z); o[3] = f2bf(w0.w);
    o[4] = f2bf(w1.x); o[5] = f2bf(w1.y); o[6] = f2bf(w1.z); o[7] = f2bf(w1.w);
    *(short8*)(wf + (size_t)pos * WF_SLOT_SHORTS + oh * 512 + lane * 8) = o;
}

// ---------------------------------------------------------------------------
// Main: 512 WGs x 512 thr (8 waves), LDS ~68 KB -> 2 WGs/CU = 16 waves/CU.
// WG owns 32 tokens (2 token-groups). Wave w processes rows r%8==w over its
// contiguous even-length schedule segment; 2 entries/iter x 4 MFMAs each.
// wf prefetch at distance 2 pairs (pure function of loop index), A-frag &
// sched prefetch at 1 pair.
// ---------------------------------------------------------------------------
__global__ __launch_bounds__(512, 4) void spmm_main_kernel(
    const float* __restrict__ x, const float* __restrict__ bias,
    const short* __restrict__ wf, const int* __restrict__ sched_g,
    const int* __restrict__ wstart_g, float* __restrict__ out)
{
    __shared__ short xs[T_TILE * XS_STRIDE];   // 66560 B
    __shared__ int ssched[SCHED_ALLOC];        // 1216 B
    __shared__ int swstart[NW + 1];

    const int tid = threadIdx.x;
    const int n0 = blockIdx.x * T_TILE;

    // Stage x tile -> LDS bf16: 4 rows/iter, 128 thr/row x 8 cols (coalesced
    // dwordx4 pairs), short8 stores, conflict-free stride.
    {
        const int tr = tid >> 7;       // 0..3
        const int tc = tid & 127;      // col octet
        const float* xp = x + (size_t)(n0 + tr) * IN_F + tc * 8;
        short* sp = xs + tr * XS_STRIDE + tc * 8;
#pragma unroll
        for (int it = 0; it < T_TILE / 4; ++it) {
            const float4 a = *(const float4*)xp;
            const float4 b = *(const float4*)(xp + 4);
            short8 s;
            s[0] = f2bf(a.x); s[1] = f2bf(a.y); s[2] = f2bf(a.z); s[3] = f2bf(a.w);
            s[4] = f2bf(b.x); s[5] = f2bf(b.y); s[6] = f2bf(b.z); s[7] = f2bf(b.w);
            *(short8*)sp = s;
            xp += 4 * IN_F;
            sp += 4 * XS_STRIDE;
        }
    }
    if (tid < SCHED_ALLOC) ssched[tid] = sched_g[tid];
    if (tid < NW + 1) swstart[tid] = wstart_g[tid];
    __syncthreads();

    const int lane = tid & 63;
    const int wave = tid >> 6;         // 0..7
    const int l16 = lane & 15, quad = lane >> 4;

    const int s = swstart[wave];
    const int e = swstart[wave + 1];   // even length >= 4

    const short* x0 = xs + l16 * XS_STRIDE + quad * 8;   // token group 0
    const short* x1 = x0 + 16 * XS_STRIDE;               // token group 1
    const short* wfl = wf + lane * 8;

    // ---- prologue: current pair (s,s+1) + next pair (s+2,s+3) ----
    int e0 = ssched[s], e1 = ssched[s + 1];
    int e2 = ssched[s + 2], e3 = ssched[s + 3];
    short8 cwA0 = *(const short8*)(wfl + (size_t)s * WF_SLOT_SHORTS);
    short8 cwB0 = *(const short8*)(wfl + (size_t)s * WF_SLOT_SHORTS + 512);
    short8 cwA1 = *(const short8*)(wfl + (size_t)(s + 1) * WF_SLOT_SHORTS);
    short8 cwB1 = *(const short8*)(wfl + (size_t)(s + 1) * WF_SLOT_SHORTS + 512);
    short8 nwA0 = *(const short8*)(wfl + (size_t)(s + 2) * WF_SLOT_SHORTS);
    short8 nwB0 = *(const short8*)(wfl + (size_t)(s + 2) * WF_SLOT_SHORTS + 512);
    short8 nwA1 = *(const short8*)(wfl + (size_t)(s + 3) * WF_SLOT_SHORTS);
    short8 nwB1 = *(const short8*)(wfl + (size_t)(s + 3) * WF_SLOT_SHORTS + 512);
    short8 a0t0 = *(const short8*)(x0 + (e0 & 31) * BW);
    short8 a0t1 = *(const short8*)(x1 + (e0 & 31) * BW);
    short8 a1t0 = *(const short8*)(x0 + (e1 & 31) * BW);
    short8 a1t1 = *(const short8*)(x1 + (e1 & 31) * BW);

    // Rolling bias, one flush ahead: wave w flushes rows w, w+8, w+16, w+24.
    int rn = wave;
    float bv0 = bias[rn * BH + l16];
    float bv1 = bias[rn * BH + 16 + l16];

    float4v accA = {0.f, 0.f, 0.f, 0.f};   // tg0, cols +0..15
    float4v accB = {0.f, 0.f, 0.f, 0.f};   // tg0, cols +16..31
    float4v accC = {0.f, 0.f, 0.f, 0.f};   // tg1, cols +0..15
    float4v accD = {0.f, 0.f, 0.f, 0.f};   // tg1, cols +16..31

    auto flush = [&](int ev) {
        if (ev & FLUSH_BIT) {              // wave-uniform in practice
            const int rr = (ev >> 5) & 31;
            const int ob = rr * BH + l16;
            float* op0 = out + (size_t)(n0 + quad * 4) * OUT_F + ob;
            float* op1 = op0 + (size_t)16 * OUT_F;
#pragma unroll
            for (int g = 0; g < 4; ++g) {  // token = tg*16 + quad*4 + g (C/D layout)
                op0[g * OUT_F]      = accA[g] + bv0;
                op0[g * OUT_F + 16] = accB[g] + bv1;
                op1[g * OUT_F]      = accC[g] + bv0;
                op1[g * OUT_F + 16] = accD[g] + bv1;
            }
            accA = (float4v){0.f, 0.f, 0.f, 0.f};
            accB = (float4v){0.f, 0.f, 0.f, 0.f};
            accC = (float4v){0.f, 0.f, 0.f, 0.f};
            accD = (float4v){0.f, 0.f, 0.f, 0.f};
            rn = (rn + NW) & 31;           // wraps harmlessly after last row
            bv0 = bias[rn * BH + l16];
            bv1 = bias[rn * BH + 16 + l16];
        }
    };

    for (int k = s; k < e; k += 2) {
        // prefetch pair k+4 (wf: distance 2 pairs; pads/overread slots make
        // every access unconditionally in-bounds)
        const int e4 = ssched[k + 4];
        const int e5 = ssched[k + 5];
        const short8 fwA0 = *(const short8*)(wfl + (size_t)(k + 4) * WF_SLOT_SHORTS);
        const short8 fwB0 = *(const short8*)(wfl + (size_t)(k + 4) * WF_SLOT_SHORTS + 512);
        const short8 fwA1 = *(const short8*)(wfl + (size_t)(k + 5) * WF_SLOT_SHORTS);
        const short8 fwB1 = *(const short8*)(wfl + (size_t)(k + 5) * WF_SLOT_SHORTS + 512);
        // A-frags for pair k+2 (LDS, distance 1 pair)
        const short8 na0t0 = *(const short8*)(x0 + (e2 & 31) * BW);
        const short8 na0t1 = *(const short8*)(x1 + (e2 & 31) * BW);
        const short8 na1t0 = *(const short8*)(x0 + (e3 & 31) * BW);
        const short8 na1t1 = *(const short8*)(x1 + (e3 & 31) * BW);

        // entry k
        accA = __builtin_amdgcn_mfma_f32_16x16x32_bf16(a0t0, cwA0, accA, 0, 0, 0);
        accB = __builtin_amdgcn_mfma_f32_16x16x32_bf16(a0t0, cwB0, accB, 0, 0, 0);
        accC = __builtin_amdgcn_mfma_f32_16x16x32_bf16(a0t1, cwA0, accC, 0, 0, 0);
        accD = __builtin_amdgcn_mfma_f32_16x16x32_bf16(a0t1, cwB0, accD, 0, 0, 0);
        flush(e0);
        // entry k+1
        accA = __builtin_amdgcn_mfma_f32_16x16x32_bf16(a1t0, cwA1, accA, 0, 0, 0);
        accB = __builtin_amdgcn_mfma_f32_16x16x32_bf16(a1t0, cwB1, accB, 0, 0, 0);
        accC = __builtin_amdgcn_mfma_f32_16x16x32_bf16(a1t1, cwA1, accC, 0, 0, 0);
        accD = __builtin_amdgcn_mfma_f32_16x16x32_bf16(a1t1, cwB1, accD, 0, 0, 0);
        flush(e1);

        // rotate pipeline
        e0 = e2; e1 = e3; e2 = e4; e3 = e5;
        a0t0 = na0t0; a0t1 = na0t1; a1t0 = na1t0; a1t1 = na1t1;
        cwA0 = nwA0; cwB0 = nwB0; cwA1 = nwA1; cwB1 = nwB1;
        nwA0 = fwA0; nwB0 = fwB0; nwA1 = fwA1; nwB1 = fwB1;
    }
}

extern "C" void kernel_launch(void* const* d_in, const int* in_sizes, int n_in,
                              void* d_out, int out_size, void* d_ws, size_t ws_size,
                              hipStream_t stream) {
    const float* x    = (const float*)d_in[0];
    const float* wd   = (const float*)d_in[1];
    const float* bias = (const float*)d_in[2];
    const int* brow   = (const int*)d_in[3];
    const int* bcol   = (const int*)d_in[4];
    float* out = (float*)d_out;

    char* ws = (char*)d_ws;                 // needs ~625 KB
    short* wf   = (short*)ws;
    int* sched  = (int*)(ws + WS_SCHED_OFF);
    int* pos_of = (int*)(ws + WS_POS_OFF);
    int* wstart = (int*)(ws + WS_WSTART_OFF);

    prep_sched_kernel<<<1, 256, 0, stream>>>(brow, bcol, sched, pos_of, wstart, wf);
    prep_w_kernel<<<NB * 128 / 256, 256, 0, stream>>>(wd, pos_of, wf);
    spmm_main_kernel<<<N_TOKENS / T_TILE, 512, 0, stream>>>(x, bias, wf, sched, wstart, out);
}